// Round 6
// baseline (530.661 us; speedup 1.0000x reference)
//
#include <hip/hip_runtime.h>
#include <math.h>

typedef float  f32x4 __attribute__((ext_vector_type(4)));
typedef short  s16x8 __attribute__((ext_vector_type(8)));
typedef unsigned short u16x8 __attribute__((ext_vector_type(8)));
typedef unsigned int   u32x4 __attribute__((ext_vector_type(4)));

constexpr int TOKENS  = 16384;
constexpr int DIM     = 4096;
constexpr int NE      = 64;
constexpr int TOPK    = 8;
constexpr int KB      = 32;          // k per chunk
constexpr int NIT     = DIM / KB;    // 128 chunks total
constexpr int WAVES   = 8;           // within-block K-split factor
constexpr int KSL     = DIM / WAVES; // 512 floats per wave slice
constexpr int NITW    = KSL / KB;    // 16 chunks per wave
constexpr int LISTCAP = 16384;
constexpr float GAPTH = 1e-4f;       // flag threshold (phase-1 err ~2e-5)

// workspace layout:
// [wpk: 1 MiB][wsI: 68 KiB][wsI2 (diag): 68 KiB][out2 (diag): 1 MiB]
constexpr unsigned WARR_U16    = (unsigned)NIT * 4 * 64 * 8;                 // 262144
constexpr size_t   WS_INT_OFF  = (size_t)WARR_U16 * 2 * sizeof(unsigned short); // 1 MiB
constexpr size_t   WS_INT2_OFF = WS_INT_OFF + 0x11000;
constexpr size_t   WS_OUT2_OFF = WS_INT2_OFF + 0x11000;
constexpr size_t   WS_MIN      = WS_INT2_OFF;                 // fast path, no diagnostics
constexpr size_t   WS_NEEDED   = WS_OUT2_OFF + (size_t)2 * TOKENS * TOPK * 4;

__device__ __forceinline__ unsigned short bf_rne(float f) {
    unsigned u = __float_as_uint(f);
    u += 0x7FFFu + ((u >> 16) & 1u);
    return (unsigned short)(u >> 16);
}
__device__ __forceinline__ float bf_f32(unsigned short h) {
    return __uint_as_float(((unsigned)h) << 16);
}
// pack two floats -> (hi bf16 pair, lo bf16 pair)
__device__ __forceinline__ uint2 cvt_pair(float f0, float f1) {
    unsigned short h0 = bf_rne(f0);
    unsigned short h1 = bf_rne(f1);
    uint2 r;
    r.x = (unsigned)h0 | ((unsigned)h1 << 16);
    r.y = (unsigned)bf_rne(f0 - bf_f32(h0)) | ((unsigned)bf_rne(f1 - bf_f32(h1)) << 16);
    return r;
}
union Cvt { u32x4 u; s16x8 s; };

// ---- W -> bf16 hi/lo planes, arranged in exact B-fragment order ----------
// elem index = ((it*4 + T)*64 + lane)*8 + j ; lane=(lq,ln): expert=16T+ln, k=32it+8lq+j
__global__ __launch_bounds__(256)
void wconv_kernel(const float* __restrict__ W, unsigned short* __restrict__ wpk,
                  int* __restrict__ wsI, int* __restrict__ wsI2)
{
    unsigned tid = blockIdx.x * 256u + threadIdx.x;
    if (tid == 0) wsI[0] = 0;                 // counter zero (wconv precedes gemm)
    if (tid == 1 && wsI2 != nullptr) wsI2[0] = 0;   // diagnostic-dispatch counter
    unsigned j    = tid & 7u;
    unsigned lane = (tid >> 3) & 63u;
    unsigned T    = (tid >> 9) & 3u;
    unsigned it   = tid >> 11;
    unsigned e = 16u * T + (lane & 15u);
    unsigned k = 32u * it + 8u * (lane >> 4) + j;
    float v = W[(size_t)e * DIM + k];
    unsigned short h = bf_rne(v);
    wpk[tid]            = h;
    wpk[WARR_U16 + tid] = bf_rne(v - bf_f32(h));
}

// ---- main: 8-wave within-block K-split GEMM + top-k ----------------------
// v6: spill-proof variant. launch_bounds(512,2) -> up to 256 VGPRs, spilling
// structurally impossible (v3/v4 evidence: allocator silently spills to meet
// tighter caps). Peak live ~95 VGPR: acc 16 + x-rot(3-deep) ~28 + phased-B 16
// + cvt temps + pointers, so occupancy likely still 4 waves/SIMD.
// B-tiles loaded in two phases (0-1 then 2-3) to halve peak B-live regs.
__global__ __launch_bounds__(512, 2)
void gemm_topk_v6(const float* __restrict__ x,
                  const unsigned short* __restrict__ wpk,
                  float* __restrict__ out, int* __restrict__ wsI)
{
    __shared__ float part[WAVES][16][NE + 4];
    __shared__ float outls[16][NE + 4];

    const int t    = threadIdx.x;
    const int ws   = t >> 6;
    const int l    = t & 63;
    const int lq   = l >> 4;
    const int ln   = l & 15;
    const int tok0 = blockIdx.x * 16;

    const float* xg = x + (size_t)(tok0 + ln) * DIM + ws * KSL + 8 * lq;
    const s16x8* bp = (const s16x8*)wpk + ws * NITW * 256 + l;   // hi plane, running
    const float* xq = xg + 3 * KB;                               // prefetch cursor

    f32x4 acc[4];
#pragma unroll
    for (int T = 0; T < 4; ++T) acc[T] = (f32x4){0.f, 0.f, 0.f, 0.f};

    // x pipeline depth 3 (~1800 cyc of cover at ~600-cyc iterations)
    float4 xa0 = *(const float4*)(xg + 0);
    float4 xa1 = *(const float4*)(xg + 4);
    float4 xb0 = *(const float4*)(xg + KB + 0);
    float4 xb1 = *(const float4*)(xg + KB + 4);
    float4 xc0 = *(const float4*)(xg + 2 * KB + 0);
    float4 xc1 = *(const float4*)(xg + 2 * KB + 4);

#pragma unroll 1
    for (int it = 0; it < NITW; ++it) {
        const s16x8* hp = bp;
        const s16x8* lp = bp + (WARR_U16 / 8);

        // phase-A B fragments (tiles 0,1)
        s16x8 bh0 = hp[0], bh1 = hp[64];
        s16x8 bl0 = lp[0], bl1 = lp[64];

        // prefetch x chunk it+3
        float4 xn0 = *(const float4*)(xq + 0);
        float4 xn1 = *(const float4*)(xq + 4);
        if (it + 4 < NITW) xq += KB;

        // fp32 -> bf16 hi/lo in registers (independent VALU, hides B latency)
        uint2 p0 = cvt_pair(xa0.x, xa0.y);
        uint2 p1 = cvt_pair(xa0.z, xa0.w);
        uint2 p2 = cvt_pair(xa1.x, xa1.y);
        uint2 p3 = cvt_pair(xa1.z, xa1.w);
        Cvt ch, cl;
        ch.u = (u32x4){p0.x, p1.x, p2.x, p3.x};
        cl.u = (u32x4){p0.y, p1.y, p2.y, p3.y};
        s16x8 ah = ch.s, al = cl.s;

        // phase A: tiles 0,1
        acc[0] = __builtin_amdgcn_mfma_f32_16x16x32_bf16(ah, bh0, acc[0], 0, 0, 0);
        acc[1] = __builtin_amdgcn_mfma_f32_16x16x32_bf16(ah, bh1, acc[1], 0, 0, 0);
        acc[0] = __builtin_amdgcn_mfma_f32_16x16x32_bf16(ah, bl0, acc[0], 0, 0, 0);
        acc[1] = __builtin_amdgcn_mfma_f32_16x16x32_bf16(ah, bl1, acc[1], 0, 0, 0);
        acc[0] = __builtin_amdgcn_mfma_f32_16x16x32_bf16(al, bh0, acc[0], 0, 0, 0);
        acc[1] = __builtin_amdgcn_mfma_f32_16x16x32_bf16(al, bh1, acc[1], 0, 0, 0);

        // phase-B B fragments (tiles 2,3) — issued late to cap live regs
        s16x8 bh2 = hp[128], bh3 = hp[192];
        s16x8 bl2 = lp[128], bl3 = lp[192];

        acc[2] = __builtin_amdgcn_mfma_f32_16x16x32_bf16(ah, bh2, acc[2], 0, 0, 0);
        acc[3] = __builtin_amdgcn_mfma_f32_16x16x32_bf16(ah, bh3, acc[3], 0, 0, 0);
        acc[2] = __builtin_amdgcn_mfma_f32_16x16x32_bf16(ah, bl2, acc[2], 0, 0, 0);
        acc[3] = __builtin_amdgcn_mfma_f32_16x16x32_bf16(ah, bl3, acc[3], 0, 0, 0);
        acc[2] = __builtin_amdgcn_mfma_f32_16x16x32_bf16(al, bh2, acc[2], 0, 0, 0);
        acc[3] = __builtin_amdgcn_mfma_f32_16x16x32_bf16(al, bh3, acc[3], 0, 0, 0);

        bp += 256;
        xa0 = xb0; xa1 = xb1; xb0 = xc0; xb1 = xc1; xc0 = xn0; xc1 = xn1;
    }

    // D layout (m89-verified): col = ln, row = 4*lq + r
#pragma unroll
    for (int T = 0; T < 4; ++T)
#pragma unroll
        for (int r = 0; r < 4; ++r)
            part[ws][4 * lq + r][16 * T + ln] = acc[T][r];
    __syncthreads();

    // fixed-order cross-wave reduce: 1024 outputs / 512 threads = 2 each
    for (int o = t; o < 16 * NE; o += 512) {
        const int ti = o >> 6, e = o & 63;
        float s = 0.f;
#pragma unroll
        for (int w2 = 0; w2 < WAVES; ++w2) s += part[w2][ti][e];
        outls[ti][e] = s;
    }
    __syncthreads();

    // top-9 scan + gap flag + fp32 softmax: one thread per token
    if (t < 16) {
        const int tok = tok0 + t;
        float v[9]; int idx[9];
#pragma unroll
        for (int j = 0; j < 9; ++j) {
            float best = -3.4e38f; int bi = 0;
            for (int e = 0; e < NE; ++e) {
                float q = outls[t][e];
                if (q > best) { best = q; bi = e; }   // lowest index wins ties
            }
            v[j] = best; idx[j] = bi;
            outls[t][bi] = -3.4e38f;
        }
        bool flag = false;
#pragma unroll
        for (int j = 0; j < 8; ++j)
            if (v[j] - v[j + 1] < GAPTH) flag = true;

        float m = v[0], s = 0.f, ex[8];
#pragma unroll
        for (int j = 0; j < 8; ++j) { ex[j] = expf(v[j] - m); s += ex[j]; }
        float inv = 1.f / s;
#pragma unroll
        for (int j = 0; j < 8; ++j) {
            out[(size_t)tok * TOPK + j] = ex[j] * inv;
            out[(size_t)TOKENS * TOPK + (size_t)tok * TOPK + j] = (float)idx[j];
        }
        if (flag) {
            int pos = atomicAdd(wsI, 1);
            if (pos < LISTCAP) wsI[16 + pos] = tok;
        }
    }
}

// exact fp64 recompute for flagged tokens (no MFMA-layout risk)
__global__ __launch_bounds__(256)
void refine_kernel(const float* __restrict__ x, const float* __restrict__ W,
                   float* __restrict__ out, const int* __restrict__ wsI)
{
    __shared__ float  xr[DIM];     // 16 KB
    __shared__ double pt[256];
    __shared__ double lg[NE];

    int cnt = wsI[0];
    if (cnt > LISTCAP) cnt = LISTCAP;
    const int t = threadIdx.x;

    for (int g = blockIdx.x; g < cnt; g += gridDim.x) {
        const int tok = wsI[16 + g];
        __syncthreads();   // previous iteration fully done before restaging
        for (int i = t; i < DIM / 4; i += 256)
            *(float4*)&xr[4 * i] = *(const float4*)&x[(size_t)tok * DIM + 4 * i];
        __syncthreads();

        const int e  = t & 63;
        const int ks = t >> 6;
        const float* wp = W + (size_t)e * DIM + ks * 1024;
        const float* xp = xr + ks * 1024;
        double p = 0.0;
        for (int i = 0; i < 256; ++i) {
            float4 wv = *(const float4*)&wp[4 * i];
            float4 xv = *(const float4*)&xp[4 * i];
            p = fma((double)xv.x, (double)wv.x, p);
            p = fma((double)xv.y, (double)wv.y, p);
            p = fma((double)xv.z, (double)wv.z, p);
            p = fma((double)xv.w, (double)wv.w, p);
        }
        pt[t] = p;
        __syncthreads();
        if (t < NE)
            lg[t] = ((pt[t] + pt[t + 64]) + pt[t + 128]) + pt[t + 192];  // fixed order
        __syncthreads();
        if (t == 0) {
            double vv[8]; int ii[8];
#pragma unroll
            for (int j = 0; j < 8; ++j) {
                double best = -1e300; int bi = 0;
                for (int e2 = 0; e2 < 64; ++e2) {
                    double q = lg[e2];
                    if (q > best) { best = q; bi = e2; }
                }
                vv[j] = best; ii[j] = bi;
                lg[bi] = -1e300;
            }
            float pf[8], ex[8], s = 0.f;
#pragma unroll
            for (int j = 0; j < 8; ++j) pf[j] = (float)vv[j];
            float m = pf[0];
#pragma unroll
            for (int j = 0; j < 8; ++j) { ex[j] = expf(pf[j] - m); s += ex[j]; }
            float inv = 1.f / s;
#pragma unroll
            for (int j = 0; j < 8; ++j) {
                out[(size_t)tok * TOPK + j] = ex[j] * inv;
                out[(size_t)TOKENS * TOPK + (size_t)tok * TOPK + j] = (float)ii[j];
            }
        }
    }
}

// =================== fallback (previous verified path) ====================
__global__ void zero_cnt_kernel(int* wsI) { if (threadIdx.x == 0) wsI[0] = 0; }

__global__ __launch_bounds__(256)
void gemm_topk_old(const float* __restrict__ x, const float* __restrict__ W,
                   float* __restrict__ out, int* __restrict__ wsI)
{
    __shared__ __align__(16) unsigned short frag[8192];
    __shared__ float ls[64][NE + 4];

    const int t    = threadIdx.x;
    const int tok0 = blockIdx.x * 64;

    const int srow = t >> 2;
    const int sq   = t & 3;
    const int sn   = srow & 15;
    const int sT   = srow >> 4;
    const int sdst = sT * 512 + (16 * sq + (sn ^ (2 * sq))) * 8;
    const float* xg = x + (size_t)(tok0 + srow) * DIM + 8 * sq;
    const float* wg = W + (size_t)srow * DIM + 8 * sq;

    const int w  = t >> 6;
    const int l  = t & 63;
    const int lq = l >> 4;
    const int ln = l & 15;
    const int fo = (16 * lq + (ln ^ (2 * lq))) * 8;

    f32x4 acc[4];
#pragma unroll
    for (int T = 0; T < 4; ++T) acc[T] = (f32x4){0.f, 0.f, 0.f, 0.f};

    float4 xa = *(const float4*)xg;
    float4 xb = *(const float4*)(xg + 4);
    float4 wa = *(const float4*)wg;
    float4 wb = *(const float4*)(wg + 4);

    for (int it = 0; it < NIT; ++it) {
        __syncthreads();
        {
            float vx[8] = {xa.x, xa.y, xa.z, xa.w, xb.x, xb.y, xb.z, xb.w};
            float vw[8] = {wa.x, wa.y, wa.z, wa.w, wb.x, wb.y, wb.z, wb.w};
            u16x8 vxh, vxl, vwh, vwl;
#pragma unroll
            for (int j = 0; j < 8; ++j) {
                unsigned short h1 = bf_rne(vx[j]);
                vxh[j] = h1;
                vxl[j] = bf_rne(vx[j] - bf_f32(h1));
                unsigned short h2 = bf_rne(vw[j]);
                vwh[j] = h2;
                vwl[j] = bf_rne(vw[j] - bf_f32(h2));
            }
            *(u16x8*)&frag[   0 + sdst] = vxh;
            *(u16x8*)&frag[2048 + sdst] = vxl;
            *(u16x8*)&frag[4096 + sdst] = vwh;
            *(u16x8*)&frag[6144 + sdst] = vwl;
        }
        __syncthreads();
        if (it + 1 < NIT) {
            const float* xp = xg + (size_t)(it + 1) * KB;
            const float* wp = wg + (size_t)(it + 1) * KB;
            xa = *(const float4*)xp;  xb = *(const float4*)(xp + 4);
            wa = *(const float4*)wp;  wb = *(const float4*)(wp + 4);
        }
        s16x8 ah = *(const s16x8*)&frag[   0 + w * 512 + fo];
        s16x8 al = *(const s16x8*)&frag[2048 + w * 512 + fo];
#pragma unroll
        for (int T = 0; T < 4; ++T) {
            s16x8 bh = *(const s16x8*)&frag[4096 + T * 512 + fo];
            s16x8 bl = *(const s16x8*)&frag[6144 + T * 512 + fo];
            acc[T] = __builtin_amdgcn_mfma_f32_16x16x32_bf16(ah, bh, acc[T], 0, 0, 0);
            acc[T] = __builtin_amdgcn_mfma_f32_16x16x32_bf16(ah, bl, acc[T], 0, 0, 0);
            acc[T] = __builtin_amdgcn_mfma_f32_16x16x32_bf16(al, bh, acc[T], 0, 0, 0);
        }
    }

    __syncthreads();
#pragma unroll
    for (int T = 0; T < 4; ++T)
#pragma unroll
        for (int r = 0; r < 4; ++r)
            ls[16 * w + 4 * lq + r][16 * T + ln] = acc[T][r];
    __syncthreads();

    if (t < 64) {
        const int tok = tok0 + t;
        float v[9]; int idx[9];
#pragma unroll
        for (int j = 0; j < 9; ++j) {
            float best = -3.4e38f; int bi = 0;
            for (int e = 0; e < NE; ++e) {
                float q = ls[t][e];
                if (q > best) { best = q; bi = e; }
            }
            v[j] = best; idx[j] = bi;
            ls[t][bi] = -3.4e38f;
        }
        bool flag = false;
#pragma unroll
        for (int j = 0; j < 8; ++j)
            if (v[j] - v[j + 1] < GAPTH) flag = true;

        float m = v[0], s = 0.f, ex[8];
#pragma unroll
        for (int j = 0; j < 8; ++j) { ex[j] = expf(v[j] - m); s += ex[j]; }
        float inv = 1.f / s;
#pragma unroll
        for (int j = 0; j < 8; ++j) {
            out[(size_t)tok * TOPK + j] = ex[j] * inv;
            out[(size_t)TOKENS * TOPK + (size_t)tok * TOPK + j] = (float)idx[j];
        }
        if (flag) {
            int pos = atomicAdd(wsI, 1);
            if (pos < LISTCAP) wsI[16 + pos] = tok;
        }
    }
}

extern "C" void kernel_launch(void* const* d_in, const int* in_sizes, int n_in,
                              void* d_out, int out_size, void* d_ws, size_t ws_size,
                              hipStream_t stream)
{
    const float* x = (const float*)d_in[0];
    const float* W = (const float*)d_in[1];
    float* out = (float*)d_out;

    if (ws_size >= WS_NEEDED) {
        // full path + diagnostic duplicate dispatch
        unsigned short* wpk = (unsigned short*)d_ws;
        int*   wsI  = (int*)((char*)d_ws + WS_INT_OFF);
        int*   wsI2 = (int*)((char*)d_ws + WS_INT2_OFF);
        float* out2 = (float*)((char*)d_ws + WS_OUT2_OFF);
        hipLaunchKernelGGL(wconv_kernel, dim3(WARR_U16 / 256), dim3(256), 0, stream, W, wpk, wsI, wsI2);
        hipLaunchKernelGGL(gemm_topk_v6, dim3(TOKENS / 16), dim3(512), 0, stream, x, wpk, out, wsI);
        // diagnostic duplicate dispatch -> scratch; gemm time = (total - 296.4us)/2
        hipLaunchKernelGGL(gemm_topk_v6, dim3(TOKENS / 16), dim3(512), 0, stream, x, wpk, out2, wsI2);
        hipLaunchKernelGGL(refine_kernel, dim3(256), dim3(256), 0, stream, x, W, out, wsI);
    } else if (ws_size >= WS_MIN) {
        // fast path without diagnostics
        unsigned short* wpk = (unsigned short*)d_ws;
        int* wsI = (int*)((char*)d_ws + WS_INT_OFF);
        hipLaunchKernelGGL(wconv_kernel, dim3(WARR_U16 / 256), dim3(256), 0, stream, W, wpk, wsI, (int*)nullptr);
        hipLaunchKernelGGL(gemm_topk_v6, dim3(TOKENS / 16), dim3(512), 0, stream, x, wpk, out, wsI);
        hipLaunchKernelGGL(refine_kernel, dim3(256), dim3(256), 0, stream, x, W, out, wsI);
    } else {
        int* wsI = (int*)d_ws;
        hipLaunchKernelGGL(zero_cnt_kernel, dim3(1), dim3(64), 0, stream, wsI);
        hipLaunchKernelGGL(gemm_topk_old, dim3(TOKENS / 64), dim3(256), 0, stream, x, W, out, wsI);
        hipLaunchKernelGGL(refine_kernel, dim3(256), dim3(256), 0, stream, x, W, out, wsI);
    }
}

// Round 7
// 523.832 us; speedup vs baseline: 1.0130x; 1.0130x over previous
//
#include <hip/hip_runtime.h>
#include <math.h>

typedef float  f32x4 __attribute__((ext_vector_type(4)));
typedef short  s16x8 __attribute__((ext_vector_type(8)));
typedef unsigned short u16x8 __attribute__((ext_vector_type(8)));
typedef unsigned int   u32x4 __attribute__((ext_vector_type(4)));

constexpr int TOKENS  = 16384;
constexpr int DIM     = 4096;
constexpr int NE      = 64;
constexpr int TOPK    = 8;
constexpr int KB      = 32;          // k per chunk
constexpr int NIT     = DIM / KB;    // 128 chunks total
constexpr int WAVES   = 8;           // within-block K-split factor
constexpr int KSL     = DIM / WAVES; // 512 floats per wave slice
constexpr int NITW    = KSL / KB;    // 16 chunks per wave
constexpr int NBLK    = TOKENS / 16; // 1024 token-tiles
constexpr int LISTCAP = 16384;
constexpr float GAPTH = 1e-4f;       // flag threshold (phase-1 err ~2e-5)

// workspace layout:
// [wpk: 1 MiB][wsI: 68 KiB][wsI2 (diag): 68 KiB][out2 (diag): 1 MiB]
constexpr unsigned WARR_U16    = (unsigned)NIT * 4 * 64 * 8;                 // 262144
constexpr size_t   WS_INT_OFF  = (size_t)WARR_U16 * 2 * sizeof(unsigned short); // 1 MiB
constexpr size_t   WS_INT2_OFF = WS_INT_OFF + 0x11000;
constexpr size_t   WS_OUT2_OFF = WS_INT2_OFF + 0x11000;
constexpr size_t   WS_MIN      = WS_INT2_OFF;                 // fast path, no diagnostics
constexpr size_t   WS_NEEDED   = WS_OUT2_OFF + (size_t)2 * TOKENS * TOPK * 4;

__device__ __forceinline__ unsigned short bf_rne(float f) {
    unsigned u = __float_as_uint(f);
    u += 0x7FFFu + ((u >> 16) & 1u);
    return (unsigned short)(u >> 16);
}
__device__ __forceinline__ float bf_f32(unsigned short h) {
    return __uint_as_float(((unsigned)h) << 16);
}
// pack two floats -> (hi bf16 pair, lo bf16 pair)
__device__ __forceinline__ uint2 cvt_pair(float f0, float f1) {
    unsigned short h0 = bf_rne(f0);
    unsigned short h1 = bf_rne(f1);
    uint2 r;
    r.x = (unsigned)h0 | ((unsigned)h1 << 16);
    r.y = (unsigned)bf_rne(f0 - bf_f32(h0)) | ((unsigned)bf_rne(f1 - bf_f32(h1)) << 16);
    return r;
}
union Cvt { u32x4 u; s16x8 s; };

// ---- W -> bf16 hi/lo planes, arranged in exact B-fragment order ----------
// elem index = ((it*4 + T)*64 + lane)*8 + j ; lane=(lq,ln): expert=16T+ln, k=32it+8lq+j
__global__ __launch_bounds__(256)
void wconv_kernel(const float* __restrict__ W, unsigned short* __restrict__ wpk,
                  int* __restrict__ wsI, int* __restrict__ wsI2)
{
    unsigned tid = blockIdx.x * 256u + threadIdx.x;
    if (tid == 0) wsI[0] = 0;                 // counter zero (wconv precedes gemm)
    if (tid == 1 && wsI2 != nullptr) wsI2[0] = 0;   // diagnostic-dispatch counter
    unsigned j    = tid & 7u;
    unsigned lane = (tid >> 3) & 63u;
    unsigned T    = (tid >> 9) & 3u;
    unsigned it   = tid >> 11;
    unsigned e = 16u * T + (lane & 15u);
    unsigned k = 32u * it + 8u * (lane >> 4) + j;
    float v = W[(size_t)e * DIM + k];
    unsigned short h = bf_rne(v);
    wpk[tid]            = h;
    wpk[WARR_U16 + tid] = bf_rne(v - bf_f32(h));
}

// ---- main: 8-wave K-split GEMM + top-k, half-pipelined B ----------------
// v7 = v6 + (a) cross-iter prefetch of phase-A B fragments (+16 VGPR; covered
// by phase-B MFMAs and next iter's cvt), (b) optional doubled grid: blocks
// >= NBLK redo the work into scratch so the single dispatch crosses the
// 160us fills and becomes visible in the top-5 counter rows.
__global__ __launch_bounds__(512, 2)
void gemm_topk_v7(const float* __restrict__ x,
                  const unsigned short* __restrict__ wpk,
                  float* __restrict__ out, int* __restrict__ wsI,
                  float* __restrict__ out2, int* __restrict__ wsI2)
{
    __shared__ float part[WAVES][16][NE + 4];
    __shared__ float outls[16][NE + 4];

    int bid = blockIdx.x;
    float* o    = out;
    int*   flg  = wsI;
    if (bid >= NBLK) { bid -= NBLK; o = out2; flg = wsI2; }

    const int t    = threadIdx.x;
    const int ws   = t >> 6;
    const int l    = t & 63;
    const int lq   = l >> 4;
    const int ln   = l & 15;
    const int tok0 = bid * 16;

    constexpr int LOFF = (int)(WARR_U16 / 8);   // s16x8 offset of lo plane

    const float* xg = x + (size_t)(tok0 + ln) * DIM + ws * KSL + 8 * lq;
    const s16x8* bp = (const s16x8*)wpk + ws * NITW * 256 + l;   // running chunk ptr
    const float* xq = xg + 3 * KB;                               // prefetch cursor

    f32x4 acc[4];
#pragma unroll
    for (int T = 0; T < 4; ++T) acc[T] = (f32x4){0.f, 0.f, 0.f, 0.f};

    // x pipeline depth 3
    float4 xa0 = *(const float4*)(xg + 0);
    float4 xa1 = *(const float4*)(xg + 4);
    float4 xb0 = *(const float4*)(xg + KB + 0);
    float4 xb1 = *(const float4*)(xg + KB + 4);
    float4 xc0 = *(const float4*)(xg + 2 * KB + 0);
    float4 xc1 = *(const float4*)(xg + 2 * KB + 4);

    // phase-A B fragments of chunk 0, preloaded (pipeline prologue)
    s16x8 pa0 = bp[0],    pa1 = bp[64];          // bh0, bh1
    s16x8 pa2 = bp[LOFF], pa3 = bp[LOFF + 64];   // bl0, bl1

#pragma unroll 1
    for (int it = 0; it < NITW; ++it) {
        const s16x8* hp = bp;
        const s16x8* lp = bp + LOFF;

        // phase-B B fragments (current chunk) — latency covered by cvt + phase-A MFMAs
        s16x8 bh2 = hp[128], bh3 = hp[192];
        s16x8 bl2 = lp[128], bl3 = lp[192];

        // prefetch x chunk it+3
        float4 xn0 = *(const float4*)(xq + 0);
        float4 xn1 = *(const float4*)(xq + 4);
        if (it + 4 < NITW) xq += KB;

        // fp32 -> bf16 hi/lo in registers (independent VALU)
        uint2 p0 = cvt_pair(xa0.x, xa0.y);
        uint2 p1 = cvt_pair(xa0.z, xa0.w);
        uint2 p2 = cvt_pair(xa1.x, xa1.y);
        uint2 p3 = cvt_pair(xa1.z, xa1.w);
        Cvt ch, cl;
        ch.u = (u32x4){p0.x, p1.x, p2.x, p3.x};
        cl.u = (u32x4){p0.y, p1.y, p2.y, p3.y};
        s16x8 ah = ch.s, al = cl.s;

        // phase A: tiles 0,1 — operands preloaded LAST iteration, no load wait
        acc[0] = __builtin_amdgcn_mfma_f32_16x16x32_bf16(ah, pa0, acc[0], 0, 0, 0);
        acc[1] = __builtin_amdgcn_mfma_f32_16x16x32_bf16(ah, pa1, acc[1], 0, 0, 0);
        acc[0] = __builtin_amdgcn_mfma_f32_16x16x32_bf16(ah, pa2, acc[0], 0, 0, 0);
        acc[1] = __builtin_amdgcn_mfma_f32_16x16x32_bf16(ah, pa3, acc[1], 0, 0, 0);
        acc[0] = __builtin_amdgcn_mfma_f32_16x16x32_bf16(al, pa0, acc[0], 0, 0, 0);
        acc[1] = __builtin_amdgcn_mfma_f32_16x16x32_bf16(al, pa1, acc[1], 0, 0, 0);

        // preload phase-A of NEXT chunk (covered by phase-B MFMAs + next cvt)
        const s16x8* bpn = (it + 1 < NITW) ? bp + 256 : bp;
        s16x8 na0 = bpn[0],    na1 = bpn[64];
        s16x8 na2 = bpn[LOFF], na3 = bpn[LOFF + 64];

        // phase B: tiles 2,3
        acc[2] = __builtin_amdgcn_mfma_f32_16x16x32_bf16(ah, bh2, acc[2], 0, 0, 0);
        acc[3] = __builtin_amdgcn_mfma_f32_16x16x32_bf16(ah, bh3, acc[3], 0, 0, 0);
        acc[2] = __builtin_amdgcn_mfma_f32_16x16x32_bf16(ah, bl2, acc[2], 0, 0, 0);
        acc[3] = __builtin_amdgcn_mfma_f32_16x16x32_bf16(ah, bl3, acc[3], 0, 0, 0);
        acc[2] = __builtin_amdgcn_mfma_f32_16x16x32_bf16(al, bh2, acc[2], 0, 0, 0);
        acc[3] = __builtin_amdgcn_mfma_f32_16x16x32_bf16(al, bh3, acc[3], 0, 0, 0);

        pa0 = na0; pa1 = na1; pa2 = na2; pa3 = na3;
        bp  = bpn;
        xa0 = xb0; xa1 = xb1; xb0 = xc0; xb1 = xc1; xc0 = xn0; xc1 = xn1;
    }

    // D layout (m89-verified): col = ln, row = 4*lq + r
#pragma unroll
    for (int T = 0; T < 4; ++T)
#pragma unroll
        for (int r = 0; r < 4; ++r)
            part[ws][4 * lq + r][16 * T + ln] = acc[T][r];
    __syncthreads();

    // fixed-order cross-wave reduce: 1024 outputs / 512 threads = 2 each
    for (int o2 = t; o2 < 16 * NE; o2 += 512) {
        const int ti = o2 >> 6, e = o2 & 63;
        float s = 0.f;
#pragma unroll
        for (int w2 = 0; w2 < WAVES; ++w2) s += part[w2][ti][e];
        outls[ti][e] = s;
    }
    __syncthreads();

    // top-9 scan + gap flag + fp32 softmax: one thread per token
    if (t < 16) {
        const int tok = tok0 + t;
        float v[9]; int idx[9];
#pragma unroll
        for (int j = 0; j < 9; ++j) {
            float best = -3.4e38f; int bi = 0;
            for (int e = 0; e < NE; ++e) {
                float q = outls[t][e];
                if (q > best) { best = q; bi = e; }   // lowest index wins ties
            }
            v[j] = best; idx[j] = bi;
            outls[t][bi] = -3.4e38f;
        }
        bool flag = false;
#pragma unroll
        for (int j = 0; j < 8; ++j)
            if (v[j] - v[j + 1] < GAPTH) flag = true;

        float m = v[0], s = 0.f, ex[8];
#pragma unroll
        for (int j = 0; j < 8; ++j) { ex[j] = expf(v[j] - m); s += ex[j]; }
        float inv = 1.f / s;
#pragma unroll
        for (int j = 0; j < 8; ++j) {
            o[(size_t)tok * TOPK + j] = ex[j] * inv;
            o[(size_t)TOKENS * TOPK + (size_t)tok * TOPK + j] = (float)idx[j];
        }
        if (flag) {
            int pos = atomicAdd(flg, 1);
            if (pos < LISTCAP) flg[16 + pos] = tok;
        }
    }
}

// exact fp64 recompute for flagged tokens (no MFMA-layout risk)
__global__ __launch_bounds__(256)
void refine_kernel(const float* __restrict__ x, const float* __restrict__ W,
                   float* __restrict__ out, const int* __restrict__ wsI)
{
    __shared__ float  xr[DIM];     // 16 KB
    __shared__ double pt[256];
    __shared__ double lg[NE];

    int cnt = wsI[0];
    if (cnt > LISTCAP) cnt = LISTCAP;
    const int t = threadIdx.x;

    for (int g = blockIdx.x; g < cnt; g += gridDim.x) {
        const int tok = wsI[16 + g];
        __syncthreads();   // previous iteration fully done before restaging
        for (int i = t; i < DIM / 4; i += 256)
            *(float4*)&xr[4 * i] = *(const float4*)&x[(size_t)tok * DIM + 4 * i];
        __syncthreads();

        const int e  = t & 63;
        const int ks = t >> 6;
        const float* wp = W + (size_t)e * DIM + ks * 1024;
        const float* xp = xr + ks * 1024;
        double p = 0.0;
        for (int i = 0; i < 256; ++i) {
            float4 wv = *(const float4*)&wp[4 * i];
            float4 xv = *(const float4*)&xp[4 * i];
            p = fma((double)xv.x, (double)wv.x, p);
            p = fma((double)xv.y, (double)wv.y, p);
            p = fma((double)xv.z, (double)wv.z, p);
            p = fma((double)xv.w, (double)wv.w, p);
        }
        pt[t] = p;
        __syncthreads();
        if (t < NE)
            lg[t] = ((pt[t] + pt[t + 64]) + pt[t + 128]) + pt[t + 192];  // fixed order
        __syncthreads();
        if (t == 0) {
            double vv[8]; int ii[8];
#pragma unroll
            for (int j = 0; j < 8; ++j) {
                double best = -1e300; int bi = 0;
                for (int e2 = 0; e2 < 64; ++e2) {
                    double q = lg[e2];
                    if (q > best) { best = q; bi = e2; }
                }
                vv[j] = best; ii[j] = bi;
                lg[bi] = -1e300;
            }
            float pf[8], ex[8], s = 0.f;
#pragma unroll
            for (int j = 0; j < 8; ++j) pf[j] = (float)vv[j];
            float m = pf[0];
#pragma unroll
            for (int j = 0; j < 8; ++j) { ex[j] = expf(pf[j] - m); s += ex[j]; }
            float inv = 1.f / s;
#pragma unroll
            for (int j = 0; j < 8; ++j) {
                out[(size_t)tok * TOPK + j] = ex[j] * inv;
                out[(size_t)TOKENS * TOPK + (size_t)tok * TOPK + j] = (float)ii[j];
            }
        }
    }
}

// =================== fallback (previous verified path) ====================
__global__ void zero_cnt_kernel(int* wsI) { if (threadIdx.x == 0) wsI[0] = 0; }

__global__ __launch_bounds__(256)
void gemm_topk_old(const float* __restrict__ x, const float* __restrict__ W,
                   float* __restrict__ out, int* __restrict__ wsI)
{
    __shared__ __align__(16) unsigned short frag[8192];
    __shared__ float ls[64][NE + 4];

    const int t    = threadIdx.x;
    const int tok0 = blockIdx.x * 64;

    const int srow = t >> 2;
    const int sq   = t & 3;
    const int sn   = srow & 15;
    const int sT   = srow >> 4;
    const int sdst = sT * 512 + (16 * sq + (sn ^ (2 * sq))) * 8;
    const float* xg = x + (size_t)(tok0 + srow) * DIM + 8 * sq;
    const float* wg = W + (size_t)srow * DIM + 8 * sq;

    const int w  = t >> 6;
    const int l  = t & 63;
    const int lq = l >> 4;
    const int ln = l & 15;
    const int fo = (16 * lq + (ln ^ (2 * lq))) * 8;

    f32x4 acc[4];
#pragma unroll
    for (int T = 0; T < 4; ++T) acc[T] = (f32x4){0.f, 0.f, 0.f, 0.f};

    float4 xa = *(const float4*)xg;
    float4 xb = *(const float4*)(xg + 4);
    float4 wa = *(const float4*)wg;
    float4 wb = *(const float4*)(wg + 4);

    for (int it = 0; it < NIT; ++it) {
        __syncthreads();
        {
            float vx[8] = {xa.x, xa.y, xa.z, xa.w, xb.x, xb.y, xb.z, xb.w};
            float vw[8] = {wa.x, wa.y, wa.z, wa.w, wb.x, wb.y, wb.z, wb.w};
            u16x8 vxh, vxl, vwh, vwl;
#pragma unroll
            for (int j = 0; j < 8; ++j) {
                unsigned short h1 = bf_rne(vx[j]);
                vxh[j] = h1;
                vxl[j] = bf_rne(vx[j] - bf_f32(h1));
                unsigned short h2 = bf_rne(vw[j]);
                vwh[j] = h2;
                vwl[j] = bf_rne(vw[j] - bf_f32(h2));
            }
            *(u16x8*)&frag[   0 + sdst] = vxh;
            *(u16x8*)&frag[2048 + sdst] = vxl;
            *(u16x8*)&frag[4096 + sdst] = vwh;
            *(u16x8*)&frag[6144 + sdst] = vwl;
        }
        __syncthreads();
        if (it + 1 < NIT) {
            const float* xp = xg + (size_t)(it + 1) * KB;
            const float* wp = wg + (size_t)(it + 1) * KB;
            xa = *(const float4*)xp;  xb = *(const float4*)(xp + 4);
            wa = *(const float4*)wp;  wb = *(const float4*)(wp + 4);
        }
        s16x8 ah = *(const s16x8*)&frag[   0 + w * 512 + fo];
        s16x8 al = *(const s16x8*)&frag[2048 + w * 512 + fo];
#pragma unroll
        for (int T = 0; T < 4; ++T) {
            s16x8 bh = *(const s16x8*)&frag[4096 + T * 512 + fo];
            s16x8 bl = *(const s16x8*)&frag[6144 + T * 512 + fo];
            acc[T] = __builtin_amdgcn_mfma_f32_16x16x32_bf16(ah, bh, acc[T], 0, 0, 0);
            acc[T] = __builtin_amdgcn_mfma_f32_16x16x32_bf16(ah, bl, acc[T], 0, 0, 0);
            acc[T] = __builtin_amdgcn_mfma_f32_16x16x32_bf16(al, bh, acc[T], 0, 0, 0);
        }
    }

    __syncthreads();
#pragma unroll
    for (int T = 0; T < 4; ++T)
#pragma unroll
        for (int r = 0; r < 4; ++r)
            ls[16 * w + 4 * lq + r][16 * T + ln] = acc[T][r];
    __syncthreads();

    if (t < 64) {
        const int tok = tok0 + t;
        float v[9]; int idx[9];
#pragma unroll
        for (int j = 0; j < 9; ++j) {
            float best = -3.4e38f; int bi = 0;
            for (int e = 0; e < NE; ++e) {
                float q = ls[t][e];
                if (q > best) { best = q; bi = e; }
            }
            v[j] = best; idx[j] = bi;
            ls[t][bi] = -3.4e38f;
        }
        bool flag = false;
#pragma unroll
        for (int j = 0; j < 8; ++j)
            if (v[j] - v[j + 1] < GAPTH) flag = true;

        float m = v[0], s = 0.f, ex[8];
#pragma unroll
        for (int j = 0; j < 8; ++j) { ex[j] = expf(v[j] - m); s += ex[j]; }
        float inv = 1.f / s;
#pragma unroll
        for (int j = 0; j < 8; ++j) {
            out[(size_t)tok * TOPK + j] = ex[j] * inv;
            out[(size_t)TOKENS * TOPK + (size_t)tok * TOPK + j] = (float)idx[j];
        }
        if (flag) {
            int pos = atomicAdd(wsI, 1);
            if (pos < LISTCAP) wsI[16 + pos] = tok;
        }
    }
}

extern "C" void kernel_launch(void* const* d_in, const int* in_sizes, int n_in,
                              void* d_out, int out_size, void* d_ws, size_t ws_size,
                              hipStream_t stream)
{
    const float* x = (const float*)d_in[0];
    const float* W = (const float*)d_in[1];
    float* out = (float*)d_out;

    if (ws_size >= WS_NEEDED) {
        // single doubled dispatch: blocks >= NBLK redo work into scratch so the
        // gemm dispatch crosses the 160us poison-fills into the top-5 rows.
        unsigned short* wpk = (unsigned short*)d_ws;
        int*   wsI  = (int*)((char*)d_ws + WS_INT_OFF);
        int*   wsI2 = (int*)((char*)d_ws + WS_INT2_OFF);
        float* out2 = (float*)((char*)d_ws + WS_OUT2_OFF);
        hipLaunchKernelGGL(wconv_kernel, dim3(WARR_U16 / 256), dim3(256), 0, stream, W, wpk, wsI, wsI2);
        hipLaunchKernelGGL(gemm_topk_v7, dim3(2 * NBLK), dim3(512), 0, stream, x, wpk, out, wsI, out2, wsI2);
        hipLaunchKernelGGL(refine_kernel, dim3(256), dim3(256), 0, stream, x, W, out, wsI);
    } else if (ws_size >= WS_MIN) {
        // fast path without diagnostics
        unsigned short* wpk = (unsigned short*)d_ws;
        int* wsI = (int*)((char*)d_ws + WS_INT_OFF);
        hipLaunchKernelGGL(wconv_kernel, dim3(WARR_U16 / 256), dim3(256), 0, stream, W, wpk, wsI, (int*)nullptr);
        hipLaunchKernelGGL(gemm_topk_v7, dim3(NBLK), dim3(512), 0, stream, x, wpk, out, wsI, out, wsI);
        hipLaunchKernelGGL(refine_kernel, dim3(256), dim3(256), 0, stream, x, W, out, wsI);
    } else {
        int* wsI = (int*)d_ws;
        hipLaunchKernelGGL(zero_cnt_kernel, dim3(1), dim3(64), 0, stream, wsI);
        hipLaunchKernelGGL(gemm_topk_old, dim3(TOKENS / 64), dim3(256), 0, stream, x, W, out, wsI);
        hipLaunchKernelGGL(refine_kernel, dim3(256), dim3(256), 0, stream, x, W, out, wsI);
    }
}

// Round 8
// 417.509 us; speedup vs baseline: 1.2710x; 1.2547x over previous
//
#include <hip/hip_runtime.h>
#include <math.h>

typedef float  f32x4 __attribute__((ext_vector_type(4)));
typedef short  s16x8 __attribute__((ext_vector_type(8)));
typedef unsigned short u16x8 __attribute__((ext_vector_type(8)));
typedef unsigned int   u32x4 __attribute__((ext_vector_type(4)));

constexpr int TOKENS  = 16384;
constexpr int DIM     = 4096;
constexpr int NE      = 64;
constexpr int TOPK    = 8;
constexpr int KB      = 32;          // k per chunk
constexpr int NIT     = DIM / KB;    // 128 chunks total
constexpr int WAVES   = 8;           // within-block K-split factor
constexpr int KSL     = DIM / WAVES; // 512 floats per wave slice
constexpr int NITW    = KSL / KB;    // 16 chunks per wave
constexpr int TM      = 32;          // tokens per block (two 16-row groups)
constexpr int NBLK    = TOKENS / TM; // 512 blocks -> fully co-resident grid
constexpr int LISTCAP = 16384;
constexpr float GAPTH = 1e-4f;       // flag threshold (phase-1 err ~2e-5)

// workspace layout: [wpk: 1 MiB][wsI: 68 KiB]
constexpr unsigned WARR_U16   = (unsigned)NIT * 4 * 64 * 8;                    // 262144
constexpr size_t   WS_INT_OFF = (size_t)WARR_U16 * 2 * sizeof(unsigned short); // 1 MiB
constexpr size_t   WS_MIN     = WS_INT_OFF + 0x11000;

__device__ __forceinline__ unsigned short bf_rne(float f) {
    unsigned u = __float_as_uint(f);
    u += 0x7FFFu + ((u >> 16) & 1u);
    return (unsigned short)(u >> 16);
}
__device__ __forceinline__ float bf_f32(unsigned short h) {
    return __uint_as_float(((unsigned)h) << 16);
}
// pack two floats -> (hi bf16 pair, lo bf16 pair)
__device__ __forceinline__ uint2 cvt_pair(float f0, float f1) {
    unsigned short h0 = bf_rne(f0);
    unsigned short h1 = bf_rne(f1);
    uint2 r;
    r.x = (unsigned)h0 | ((unsigned)h1 << 16);
    r.y = (unsigned)bf_rne(f0 - bf_f32(h0)) | ((unsigned)bf_rne(f1 - bf_f32(h1)) << 16);
    return r;
}
union Cvt { u32x4 u; s16x8 s; };

// build (ah, al) A-fragments from two float4 of one token row
__device__ __forceinline__ void cvt_frag(float4 a0, float4 a1, s16x8& ah, s16x8& al) {
    uint2 p0 = cvt_pair(a0.x, a0.y);
    uint2 p1 = cvt_pair(a0.z, a0.w);
    uint2 p2 = cvt_pair(a1.x, a1.y);
    uint2 p3 = cvt_pair(a1.z, a1.w);
    Cvt ch, cl;
    ch.u = (u32x4){p0.x, p1.x, p2.x, p3.x};
    cl.u = (u32x4){p0.y, p1.y, p2.y, p3.y};
    ah = ch.s; al = cl.s;
}

// ---- W -> bf16 hi/lo planes, arranged in exact B-fragment order ----------
// elem index = ((it*4 + T)*64 + lane)*8 + j ; lane=(lq,ln): expert=16T+ln, k=32it+8lq+j
__global__ __launch_bounds__(256)
void wconv_kernel(const float* __restrict__ W, unsigned short* __restrict__ wpk,
                  int* __restrict__ wsI)
{
    unsigned tid = blockIdx.x * 256u + threadIdx.x;
    if (tid == 0) wsI[0] = 0;                 // counter zero (wconv precedes gemm)
    unsigned j    = tid & 7u;
    unsigned lane = (tid >> 3) & 63u;
    unsigned T    = (tid >> 9) & 3u;
    unsigned it   = tid >> 11;
    unsigned e = 16u * T + (lane & 15u);
    unsigned k = 32u * it + 8u * (lane >> 4) + j;
    float v = W[(size_t)e * DIM + k];
    unsigned short h = bf_rne(v);
    wpk[tid]            = h;
    wpk[WARR_U16 + tid] = bf_rne(v - bf_f32(h));
}

// ---- main: 32-token/block, 8-wave K-split GEMM + top-k -------------------
// v8: two 16-token groups per block share each B fragment -> 24 MFMA + ~100
// VALU per 8 B-loads (2x intensity vs v7; B L2 traffic halved). Grid 512 is
// fully co-resident (2 blocks/CU by LDS, 16 waves/CU). Phased B loads:
// phase-B issued between cvt(g0) and cvt(g1) -> ~160cy self-cover ~= L2 lat.
__global__ __launch_bounds__(512, 2)
void gemm_topk_v8(const float* __restrict__ x,
                  const unsigned short* __restrict__ wpk,
                  float* __restrict__ out, int* __restrict__ wsI)
{
    __shared__ float part[WAVES][TM][NE + 4];   // 69,632 B
    __shared__ float outls[TM][NE + 5];         //  8,832 B (stride 69: 5t+e banks, conflict-free scan)

    const int t    = threadIdx.x;
    const int ws   = t >> 6;
    const int l    = t & 63;
    const int lq   = l >> 4;
    const int ln   = l & 15;
    const int tok0 = blockIdx.x * TM;

    constexpr int LOFF = (int)(WARR_U16 / 8);   // s16x8 offset of lo plane

    const float* xg0 = x + (size_t)(tok0 + ln) * DIM + ws * KSL + 8 * lq;
    const float* xg1 = xg0 + (size_t)16 * DIM;
    const s16x8* bp  = (const s16x8*)wpk + ws * NITW * 256 + l;   // running chunk ptr
    const float* xq0 = xg0 + 2 * KB;                              // prefetch cursors (depth 2)
    const float* xq1 = xg1 + 2 * KB;

    f32x4 acc[8];
#pragma unroll
    for (int T = 0; T < 8; ++T) acc[T] = (f32x4){0.f, 0.f, 0.f, 0.f};

    // x pipeline depth 2, both groups
    float4 xa0 = *(const float4*)(xg0 + 0),      xa1 = *(const float4*)(xg0 + 4);
    float4 xb0 = *(const float4*)(xg0 + KB + 0), xb1 = *(const float4*)(xg0 + KB + 4);
    float4 ya0 = *(const float4*)(xg1 + 0),      ya1 = *(const float4*)(xg1 + 4);
    float4 yb0 = *(const float4*)(xg1 + KB + 0), yb1 = *(const float4*)(xg1 + KB + 4);

#pragma unroll 1
    for (int it = 0; it < NITW; ++it) {
        const s16x8* hp = bp;
        const s16x8* lp = bp + LOFF;

        // phase-A B fragments (tiles 0,1)
        s16x8 bh0 = hp[0], bh1 = hp[64];
        s16x8 bl0 = lp[0], bl1 = lp[64];

        // prefetch x chunk it+2, both groups
        float4 xn0 = *(const float4*)(xq0 + 0), xn1 = *(const float4*)(xq0 + 4);
        float4 yn0 = *(const float4*)(xq1 + 0), yn1 = *(const float4*)(xq1 + 4);
        if (it + 3 < NITW) { xq0 += KB; xq1 += KB; }

        // cvt group 0 (VALU cover for phase-A B loads)
        s16x8 ah0, al0;
        cvt_frag(xa0, xa1, ah0, al0);

        // phase-B B fragments (tiles 2,3) — cvt(g1) + phase-A MFMAs cover them
        s16x8 bh2 = hp[128], bh3 = hp[192];
        s16x8 bl2 = lp[128], bl3 = lp[192];

        // cvt group 1
        s16x8 ah1, al1;
        cvt_frag(ya0, ya1, ah1, al1);

        // phase A: tiles 0,1 for both groups (12 MFMA)
        acc[0] = __builtin_amdgcn_mfma_f32_16x16x32_bf16(ah0, bh0, acc[0], 0, 0, 0);
        acc[1] = __builtin_amdgcn_mfma_f32_16x16x32_bf16(ah0, bh1, acc[1], 0, 0, 0);
        acc[4] = __builtin_amdgcn_mfma_f32_16x16x32_bf16(ah1, bh0, acc[4], 0, 0, 0);
        acc[5] = __builtin_amdgcn_mfma_f32_16x16x32_bf16(ah1, bh1, acc[5], 0, 0, 0);
        acc[0] = __builtin_amdgcn_mfma_f32_16x16x32_bf16(ah0, bl0, acc[0], 0, 0, 0);
        acc[1] = __builtin_amdgcn_mfma_f32_16x16x32_bf16(ah0, bl1, acc[1], 0, 0, 0);
        acc[4] = __builtin_amdgcn_mfma_f32_16x16x32_bf16(ah1, bl0, acc[4], 0, 0, 0);
        acc[5] = __builtin_amdgcn_mfma_f32_16x16x32_bf16(ah1, bl1, acc[5], 0, 0, 0);
        acc[0] = __builtin_amdgcn_mfma_f32_16x16x32_bf16(al0, bh0, acc[0], 0, 0, 0);
        acc[1] = __builtin_amdgcn_mfma_f32_16x16x32_bf16(al0, bh1, acc[1], 0, 0, 0);
        acc[4] = __builtin_amdgcn_mfma_f32_16x16x32_bf16(al1, bh0, acc[4], 0, 0, 0);
        acc[5] = __builtin_amdgcn_mfma_f32_16x16x32_bf16(al1, bh1, acc[5], 0, 0, 0);

        // phase B: tiles 2,3 for both groups (12 MFMA)
        acc[2] = __builtin_amdgcn_mfma_f32_16x16x32_bf16(ah0, bh2, acc[2], 0, 0, 0);
        acc[3] = __builtin_amdgcn_mfma_f32_16x16x32_bf16(ah0, bh3, acc[3], 0, 0, 0);
        acc[6] = __builtin_amdgcn_mfma_f32_16x16x32_bf16(ah1, bh2, acc[6], 0, 0, 0);
        acc[7] = __builtin_amdgcn_mfma_f32_16x16x32_bf16(ah1, bh3, acc[7], 0, 0, 0);
        acc[2] = __builtin_amdgcn_mfma_f32_16x16x32_bf16(ah0, bl2, acc[2], 0, 0, 0);
        acc[3] = __builtin_amdgcn_mfma_f32_16x16x32_bf16(ah0, bl3, acc[3], 0, 0, 0);
        acc[6] = __builtin_amdgcn_mfma_f32_16x16x32_bf16(ah1, bl2, acc[6], 0, 0, 0);
        acc[7] = __builtin_amdgcn_mfma_f32_16x16x32_bf16(ah1, bl3, acc[7], 0, 0, 0);
        acc[2] = __builtin_amdgcn_mfma_f32_16x16x32_bf16(al0, bh2, acc[2], 0, 0, 0);
        acc[3] = __builtin_amdgcn_mfma_f32_16x16x32_bf16(al0, bh3, acc[3], 0, 0, 0);
        acc[6] = __builtin_amdgcn_mfma_f32_16x16x32_bf16(al1, bh2, acc[6], 0, 0, 0);
        acc[7] = __builtin_amdgcn_mfma_f32_16x16x32_bf16(al1, bh3, acc[7], 0, 0, 0);

        bp += 256;
        xa0 = xb0; xa1 = xb1; xb0 = xn0; xb1 = xn1;
        ya0 = yb0; ya1 = yb1; yb0 = yn0; yb1 = yn1;
    }

    // D layout (m89-verified): col = ln, row = 4*lq + r ; g1 rows offset +16
#pragma unroll
    for (int T = 0; T < 4; ++T)
#pragma unroll
        for (int r = 0; r < 4; ++r) {
            part[ws][     4 * lq + r][16 * T + ln] = acc[T][r];
            part[ws][16 + 4 * lq + r][16 * T + ln] = acc[4 + T][r];
        }
    __syncthreads();

    // fixed-order cross-wave reduce: 2048 outputs / 512 threads = 4 each
    for (int o2 = t; o2 < TM * NE; o2 += 512) {
        const int ti = o2 >> 6, e = o2 & 63;
        float s = 0.f;
#pragma unroll
        for (int w2 = 0; w2 < WAVES; ++w2) s += part[w2][ti][e];
        outls[ti][e] = s;
    }
    __syncthreads();

    // top-9 scan + gap flag + fp32 softmax: one thread per token
    if (t < TM) {
        const int tok = tok0 + t;
        float v[9]; int idx[9];
#pragma unroll
        for (int j = 0; j < 9; ++j) {
            float best = -3.4e38f; int bi = 0;
            for (int e = 0; e < NE; ++e) {
                float q = outls[t][e];
                if (q > best) { best = q; bi = e; }   // lowest index wins ties
            }
            v[j] = best; idx[j] = bi;
            outls[t][bi] = -3.4e38f;
        }
        bool flag = false;
#pragma unroll
        for (int j = 0; j < 8; ++j)
            if (v[j] - v[j + 1] < GAPTH) flag = true;

        float m = v[0], s = 0.f, ex[8];
#pragma unroll
        for (int j = 0; j < 8; ++j) { ex[j] = expf(v[j] - m); s += ex[j]; }
        float inv = 1.f / s;
#pragma unroll
        for (int j = 0; j < 8; ++j) {
            out[(size_t)tok * TOPK + j] = ex[j] * inv;
            out[(size_t)TOKENS * TOPK + (size_t)tok * TOPK + j] = (float)idx[j];
        }
        if (flag) {
            int pos = atomicAdd(wsI, 1);
            if (pos < LISTCAP) wsI[16 + pos] = tok;
        }
    }
}

// exact fp64 recompute for flagged tokens (no MFMA-layout risk)
__global__ __launch_bounds__(256)
void refine_kernel(const float* __restrict__ x, const float* __restrict__ W,
                   float* __restrict__ out, const int* __restrict__ wsI)
{
    __shared__ float  xr[DIM];     // 16 KB
    __shared__ double pt[256];
    __shared__ double lg[NE];

    int cnt = wsI[0];
    if (cnt > LISTCAP) cnt = LISTCAP;
    const int t = threadIdx.x;

    for (int g = blockIdx.x; g < cnt; g += gridDim.x) {
        const int tok = wsI[16 + g];
        __syncthreads();   // previous iteration fully done before restaging
        for (int i = t; i < DIM / 4; i += 256)
            *(float4*)&xr[4 * i] = *(const float4*)&x[(size_t)tok * DIM + 4 * i];
        __syncthreads();

        const int e  = t & 63;
        const int ks = t >> 6;
        const float* wp = W + (size_t)e * DIM + ks * 1024;
        const float* xp = xr + ks * 1024;
        double p = 0.0;
        for (int i = 0; i < 256; ++i) {
            float4 wv = *(const float4*)&wp[4 * i];
            float4 xv = *(const float4*)&xp[4 * i];
            p = fma((double)xv.x, (double)wv.x, p);
            p = fma((double)xv.y, (double)wv.y, p);
            p = fma((double)xv.z, (double)wv.z, p);
            p = fma((double)xv.w, (double)wv.w, p);
        }
        pt[t] = p;
        __syncthreads();
        if (t < NE)
            lg[t] = ((pt[t] + pt[t + 64]) + pt[t + 128]) + pt[t + 192];  // fixed order
        __syncthreads();
        if (t == 0) {
            double vv[8]; int ii[8];
#pragma unroll
            for (int j = 0; j < 8; ++j) {
                double best = -1e300; int bi = 0;
                for (int e2 = 0; e2 < 64; ++e2) {
                    double q = lg[e2];
                    if (q > best) { best = q; bi = e2; }
                }
                vv[j] = best; ii[j] = bi;
                lg[bi] = -1e300;
            }
            float pf[8], ex[8], s = 0.f;
#pragma unroll
            for (int j = 0; j < 8; ++j) pf[j] = (float)vv[j];
            float m = pf[0];
#pragma unroll
            for (int j = 0; j < 8; ++j) { ex[j] = expf(pf[j] - m); s += ex[j]; }
            float inv = 1.f / s;
#pragma unroll
            for (int j = 0; j < 8; ++j) {
                out[(size_t)tok * TOPK + j] = ex[j] * inv;
                out[(size_t)TOKENS * TOPK + (size_t)tok * TOPK + j] = (float)ii[j];
            }
        }
    }
}

// =================== fallback (previous verified path) ====================
__global__ void zero_cnt_kernel(int* wsI) { if (threadIdx.x == 0) wsI[0] = 0; }

__global__ __launch_bounds__(256)
void gemm_topk_old(const float* __restrict__ x, const float* __restrict__ W,
                   float* __restrict__ out, int* __restrict__ wsI)
{
    __shared__ __align__(16) unsigned short frag[8192];
    __shared__ float ls[64][NE + 4];

    const int t    = threadIdx.x;
    const int tok0 = blockIdx.x * 64;

    const int srow = t >> 2;
    const int sq   = t & 3;
    const int sn   = srow & 15;
    const int sT   = srow >> 4;
    const int sdst = sT * 512 + (16 * sq + (sn ^ (2 * sq))) * 8;
    const float* xg = x + (size_t)(tok0 + srow) * DIM + 8 * sq;
    const float* wg = W + (size_t)srow * DIM + 8 * sq;

    const int w  = t >> 6;
    const int l  = t & 63;
    const int lq = l >> 4;
    const int ln = l & 15;
    const int fo = (16 * lq + (ln ^ (2 * lq))) * 8;

    f32x4 acc[4];
#pragma unroll
    for (int T = 0; T < 4; ++T) acc[T] = (f32x4){0.f, 0.f, 0.f, 0.f};

    float4 xa = *(const float4*)xg;
    float4 xb = *(const float4*)(xg + 4);
    float4 wa = *(const float4*)wg;
    float4 wb = *(const float4*)(wg + 4);

    for (int it = 0; it < NIT; ++it) {
        __syncthreads();
        {
            float vx[8] = {xa.x, xa.y, xa.z, xa.w, xb.x, xb.y, xb.z, xb.w};
            float vw[8] = {wa.x, wa.y, wa.z, wa.w, wb.x, wb.y, wb.z, wb.w};
            u16x8 vxh, vxl, vwh, vwl;
#pragma unroll
            for (int j = 0; j < 8; ++j) {
                unsigned short h1 = bf_rne(vx[j]);
                vxh[j] = h1;
                vxl[j] = bf_rne(vx[j] - bf_f32(h1));
                unsigned short h2 = bf_rne(vw[j]);
                vwh[j] = h2;
                vwl[j] = bf_rne(vw[j] - bf_f32(h2));
            }
            *(u16x8*)&frag[   0 + sdst] = vxh;
            *(u16x8*)&frag[2048 + sdst] = vxl;
            *(u16x8*)&frag[4096 + sdst] = vwh;
            *(u16x8*)&frag[6144 + sdst] = vwl;
        }
        __syncthreads();
        if (it + 1 < NIT) {
            const float* xp = xg + (size_t)(it + 1) * KB;
            const float* wp = wg + (size_t)(it + 1) * KB;
            xa = *(const float4*)xp;  xb = *(const float4*)(xp + 4);
            wa = *(const float4*)wp;  wb = *(const float4*)(wp + 4);
        }
        s16x8 ah = *(const s16x8*)&frag[   0 + w * 512 + fo];
        s16x8 al = *(const s16x8*)&frag[2048 + w * 512 + fo];
#pragma unroll
        for (int T = 0; T < 4; ++T) {
            s16x8 bh = *(const s16x8*)&frag[4096 + T * 512 + fo];
            s16x8 bl = *(const s16x8*)&frag[6144 + T * 512 + fo];
            acc[T] = __builtin_amdgcn_mfma_f32_16x16x32_bf16(ah, bh, acc[T], 0, 0, 0);
            acc[T] = __builtin_amdgcn_mfma_f32_16x16x32_bf16(ah, bl, acc[T], 0, 0, 0);
            acc[T] = __builtin_amdgcn_mfma_f32_16x16x32_bf16(al, bh, acc[T], 0, 0, 0);
        }
    }

    __syncthreads();
#pragma unroll
    for (int T = 0; T < 4; ++T)
#pragma unroll
        for (int r = 0; r < 4; ++r)
            ls[16 * w + 4 * lq + r][16 * T + ln] = acc[T][r];
    __syncthreads();

    if (t < 64) {
        const int tok = tok0 + t;
        float v[9]; int idx[9];
#pragma unroll
        for (int j = 0; j < 9; ++j) {
            float best = -3.4e38f; int bi = 0;
            for (int e = 0; e < NE; ++e) {
                float q = ls[t][e];
                if (q > best) { best = q; bi = e; }
            }
            v[j] = best; idx[j] = bi;
            ls[t][bi] = -3.4e38f;
        }
        bool flag = false;
#pragma unroll
        for (int j = 0; j < 8; ++j)
            if (v[j] - v[j + 1] < GAPTH) flag = true;

        float m = v[0], s = 0.f, ex[8];
#pragma unroll
        for (int j = 0; j < 8; ++j) { ex[j] = expf(v[j] - m); s += ex[j]; }
        float inv = 1.f / s;
#pragma unroll
        for (int j = 0; j < 8; ++j) {
            out[(size_t)tok * TOPK + j] = ex[j] * inv;
            out[(size_t)TOKENS * TOPK + (size_t)tok * TOPK + j] = (float)idx[j];
        }
        if (flag) {
            int pos = atomicAdd(wsI, 1);
            if (pos < LISTCAP) wsI[16 + pos] = tok;
        }
    }
}

extern "C" void kernel_launch(void* const* d_in, const int* in_sizes, int n_in,
                              void* d_out, int out_size, void* d_ws, size_t ws_size,
                              hipStream_t stream)
{
    const float* x = (const float*)d_in[0];
    const float* W = (const float*)d_in[1];
    float* out = (float*)d_out;

    if (ws_size >= WS_MIN) {
        unsigned short* wpk = (unsigned short*)d_ws;
        int* wsI = (int*)((char*)d_ws + WS_INT_OFF);
        hipLaunchKernelGGL(wconv_kernel, dim3(WARR_U16 / 256), dim3(256), 0, stream, W, wpk, wsI);
        hipLaunchKernelGGL(gemm_topk_v8, dim3(NBLK), dim3(512), 0, stream, x, wpk, out, wsI);
        hipLaunchKernelGGL(refine_kernel, dim3(256), dim3(256), 0, stream, x, W, out, wsI);
    } else {
        int* wsI = (int*)d_ws;
        hipLaunchKernelGGL(zero_cnt_kernel, dim3(1), dim3(64), 0, stream, wsI);
        hipLaunchKernelGGL(gemm_topk_old, dim3(TOKENS / 64), dim3(256), 0, stream, x, W, out, wsI);
        hipLaunchKernelGGL(refine_kernel, dim3(256), dim3(256), 0, stream, x, W, out, wsI);
    }
}